// Round 4
// baseline (341.746 us; speedup 1.0000x reference)
//
#include <hip/hip_runtime.h>
#include <hip/hip_bf16.h>

// 2-layer GraphSAGE mean-aggr, N=100000, E=1600000, F=128.
// R14: fuse layer 1 (gather+GEMM). R13 post-mortem: csr_mean pinned at
// 57.9us / 178MB FETCH = the per-XCD traffic floor (each XCD fetches ~86%
// of the 25.6MB table once); service-rate-bound, not latency-bound (VALU
// 52->29% with no time change). So overlap the OTHER pipes with it:
// fused_sage1 gathers 64 nodes' means into LDS Ms[64][136] (no global mean
// write/read), then runs the proven MFMA GEMM with A-chunks 0-1 from Ms.
// Blocks in MFMA phase overlap blocks in gather phase -> GEMM1 time hides
// under the gather wall. h -> d_out interleaved (pitch 256 shorts).
// Layer 2 stays split (h/out share d_out slots; fusion would race):
// csr_mean<5,4> gathers h from d_out, mean2 -> xb contiguous (xb free
// after fused1); GEMM2 reads mean2(xb,128) + h(d_out,256), writes fp32
// out over the slots (own-rows-only aliasing, proven pattern).
// Gather loop / pack / MFMA order identical to R13 -> bit-identical output.

#define N_NODES 100000
#define N_EDGES 1600000
#define F 128
#define NBK 782       // ceil(N/128) buckets (128 nodes each)
#define NSB 391       // scatter blocks (4096 edges each)

typedef __attribute__((ext_vector_type(8))) short short8;
typedef __attribute__((ext_vector_type(4))) float f32x4;

__device__ __forceinline__ unsigned short f2bf(float f) {
    union { __hip_bfloat16 h; unsigned short u; } cv;
    cv.h = __float2bfloat16(f);
    return cv.u;
}
// unpack packed bf16 pair and accumulate
__device__ __forceinline__ void upadd(unsigned u, float& a, float& b) {
    a += __uint_as_float(u << 16);
    b += __uint_as_float(u & 0xffff0000u);
}

// ---------------- contention-free bucket permute (R7-proven, R11-extended) ----------------
__global__ __launch_bounds__(256) void blkhist_kernel(
    const int* __restrict__ dst, int* __restrict__ blkhist, int E)
{
    __shared__ int h[NBK];
    int t = threadIdx.x, blk = blockIdx.x;
    for (int i = t; i < NBK; i += 256) h[i] = 0;
    __syncthreads();
    int base = blk * 4096;
    int end = min(base + 4096, E);
    for (int e = base + t; e < end; e += 256) atomicAdd(&h[dst[e] >> 7], 1);
    __syncthreads();
    for (int i = t; i < NBK; i += 256) blkhist[blk * NBK + i] = h[i];
}

// per-bucket: scan over scatter blocks -> bucket-RELATIVE block bases; emit total
__global__ __launch_bounds__(512) void bucket_scan_kernel(
    const int* __restrict__ blkhist, int* __restrict__ bbase,
    int* __restrict__ btotal)
{
    __shared__ int s[512];
    int b = blockIdx.x, t = threadIdx.x;
    int v = (t < NSB) ? blkhist[t * NBK + b] : 0;
    s[t] = v;
    __syncthreads();
#pragma unroll
    for (int off = 1; off < 512; off <<= 1) {
        int u = (t >= off) ? s[t - off] : 0;
        __syncthreads();
        s[t] += u;
        __syncthreads();
    }
    if (t < NSB) bbase[t * NBK + b] = s[t] - v;   // relative to bucket start
    if (t == NSB - 1) btotal[b] = s[t];           // bucket total
}

// single block: exclusive scan of bucket totals in-place; bb[NBK] = E sentinel
__global__ __launch_bounds__(1024) void bucket_base_scan_kernel(int* bb)
{
    __shared__ int s[1024];
    int t = threadIdx.x;
    int v = (t < NBK) ? bb[t] : 0;
    s[t] = v;
    __syncthreads();
#pragma unroll
    for (int off = 1; off < 1024; off <<= 1) {
        int u = (t >= off) ? s[t - off] : 0;
        __syncthreads();
        s[t] += u;
        __syncthreads();
    }
    if (t <= NBK) bb[t] = (t == 0) ? 0 : s[t - 1];
}

__global__ __launch_bounds__(256) void bucket_scatter_kernel(
    const int* __restrict__ src, const int* __restrict__ dst,
    const int* __restrict__ bbase, const int* __restrict__ bucket_base,
    unsigned* __restrict__ staging, int E)
{
    __shared__ int cur[NBK];
    int t = threadIdx.x, blk = blockIdx.x;
    for (int i = t; i < NBK; i += 256)
        cur[i] = bbase[blk * NBK + i] + bucket_base[i];
    __syncthreads();
    int base = blk * 4096;
    int end = min(base + 4096, E);
    for (int e = base + t; e < end; e += 256) {
        int d = dst[e];
        int p = atomicAdd(&cur[d >> 7], 1);
        staging[p] = ((unsigned)src[e] << 7) | (unsigned)(d & 127);
    }
}

// pass 1: LDS-histogram the bucket's 128 node slots -> deg/rowptr; pass 2: fill
__global__ __launch_bounds__(256) void bucket_fill_kernel(
    const unsigned* __restrict__ staging, const int* __restrict__ bucket_base,
    int* __restrict__ rowptr, int* __restrict__ deg_i,
    int* __restrict__ csr_src, int N)
{
    __shared__ int cnt[128];
    __shared__ int sc[128];
    __shared__ int cur[128];
    int b = blockIdx.x;
    int t = threadIdx.x;
    if (t < 128) cnt[t] = 0;
    __syncthreads();
    int start = bucket_base[b];
    int end = bucket_base[b + 1];
    for (int e = start + t; e < end; e += 256)
        atomicAdd(&cnt[staging[e] & 127], 1);
    __syncthreads();
    // exclusive scan over 128 slot counts
    if (t < 128) sc[t] = cnt[t];
    __syncthreads();
#pragma unroll
    for (int off = 1; off < 128; off <<= 1) {
        int v = (t < 128 && t >= off) ? sc[t - off] : 0;
        __syncthreads();
        if (t < 128) sc[t] += v;
        __syncthreads();
    }
    if (t < 128) {
        int excl = sc[t] - cnt[t];
        cur[t] = start + excl;
        int node = (b << 7) + t;
        if (node < N) {
            rowptr[node] = start + excl;
            deg_i[node] = cnt[t];
        }
    }
    __syncthreads();
    for (int e = start + t; e < end; e += 256) {
        unsigned u = staging[e];
        int p = atomicAdd(&cur[u & 127], 1);
        csr_src[p] = (int)(u >> 7);
    }
}

// ---------------- weight transpose+cast: Wt[layer][col][k] bf16 ----------------
__global__ __launch_bounds__(256) void wt_kernel(
    const float* __restrict__ Wl1, const float* __restrict__ Wr1,
    const float* __restrict__ Wl2, const float* __restrict__ Wr2,
    unsigned short* __restrict__ wt)
{
    int e = blockIdx.x * 256 + threadIdx.x;   // 0..65535
    int layer = e >> 15;
    int idx = e & 32767;
    int k = idx >> 7;      // 0..255
    int c = idx & 127;
    const float* W = (layer == 0) ? (k < 128 ? Wl1 : Wr1)
                                  : (k < 128 ? Wl2 : Wr2);
    float v = W[(k & 127) * 128 + c];
    wt[layer * 32768 + c * 256 + k] = f2bf(v);
}

// ---------------- cast x -> bf16 ----------------
__global__ __launch_bounds__(256) void cast_kernel(
    const float* __restrict__ x, unsigned short* __restrict__ xb, int total4)
{
    int i = blockIdx.x * 256 + threadIdx.x;
    if (i >= total4) return;
    float4 v = ((const float4*)x)[i];
    unsigned lo = ((unsigned)f2bf(v.y) << 16) | f2bf(v.x);
    unsigned hi = ((unsigned)f2bf(v.w) << 16) | f2bf(v.z);
    ((uint2*)xb)[i] = make_uint2(lo, hi);
}

// ---------------- aggregate: mean over in-neighbors (bf16 src) ----------------
// R13 structure: one node per QUARTER-wave; lane c owns 16B (cols 8c..8c+7).
// SS = log2(src row pitch in uint4); DS = log2(dst row pitch in uint4).
template <int SS, int DS>
__global__ __launch_bounds__(256) void csr_mean_kernel(
    const uint4* __restrict__ featb4, const int* __restrict__ rowptr,
    const int* __restrict__ deg_i, const int* __restrict__ csr_src,
    uint4* __restrict__ mean4, int N)
{
    int lane = threadIdx.x & 63;
    int wv = threadIdx.x >> 6;                     // wave in block 0..3
    int c = lane & 15;                             // 16B column segment
    int qb = lane & 48;                            // quarter's shfl base
    int n = blockIdx.x * 16 + wv * 4 + (lane >> 4);
    if (n >= N) return;
    int start = rowptr[n];
    int dg = deg_i[n];

    float acc[8];
#pragma unroll
    for (int j = 0; j < 8; ++j) acc[j] = 0.f;

    for (int base = 0; base < dg; base += 16) {
        int rem = min(dg - base, 16);
        int idxw = (c < rem) ? csr_src[start + base + c] : 0;

        int e = 0;
        for (; e + 4 <= rem; e += 4) {
            int i0 = __shfl(idxw, qb + e);
            int i1 = __shfl(idxw, qb + e + 1);
            int i2 = __shfl(idxw, qb + e + 2);
            int i3 = __shfl(idxw, qb + e + 3);
            uint4 u0 = featb4[(unsigned)((i0 << SS) | c)];
            uint4 u1 = featb4[(unsigned)((i1 << SS) | c)];
            uint4 u2 = featb4[(unsigned)((i2 << SS) | c)];
            uint4 u3 = featb4[(unsigned)((i3 << SS) | c)];
            upadd(u0.x, acc[0], acc[1]);
            upadd(u0.y, acc[2], acc[3]);
            upadd(u0.z, acc[4], acc[5]);
            upadd(u0.w, acc[6], acc[7]);
            upadd(u1.x, acc[0], acc[1]);
            upadd(u1.y, acc[2], acc[3]);
            upadd(u1.z, acc[4], acc[5]);
            upadd(u1.w, acc[6], acc[7]);
            upadd(u2.x, acc[0], acc[1]);
            upadd(u2.y, acc[2], acc[3]);
            upadd(u2.z, acc[4], acc[5]);
            upadd(u2.w, acc[6], acc[7]);
            upadd(u3.x, acc[0], acc[1]);
            upadd(u3.y, acc[2], acc[3]);
            upadd(u3.z, acc[4], acc[5]);
            upadd(u3.w, acc[6], acc[7]);
        }
        for (; e < rem; ++e) {
            int i0 = __shfl(idxw, qb + e);
            uint4 u0 = featb4[(unsigned)((i0 << SS) | c)];
            upadd(u0.x, acc[0], acc[1]);
            upadd(u0.y, acc[2], acc[3]);
            upadd(u0.z, acc[4], acc[5]);
            upadd(u0.w, acc[6], acc[7]);
        }
    }

    float r = 1.0f / fmaxf((float)dg, 1.0f);
    uint4 o;
    o.x = ((unsigned)f2bf(acc[1] * r) << 16) | f2bf(acc[0] * r);
    o.y = ((unsigned)f2bf(acc[3] * r) << 16) | f2bf(acc[2] * r);
    o.z = ((unsigned)f2bf(acc[5] * r) << 16) | f2bf(acc[4] * r);
    o.w = ((unsigned)f2bf(acc[7] * r) << 16) | f2bf(acc[6] * r);
    mean4[(unsigned)((n << DS) | c)] = o;
}

// ---------------- FUSED layer 1: gather-mean into LDS + MFMA GEMM ----------------
// Block = 64 nodes. Gather phase: quarter Q handles nodes block_row+Q*4+j
// (j=0..3) with the R13 loop; mean packed bf16 into Ms[64][136] (stride
// 272B = 17x16B, conflict-free like the proven 144B As). GEMM phase:
// chunks 0-1 read A-frags from Ms (mean), chunks 2-3 stage x rows into As.
// Epilogue: relu, bf16 h -> outb pitch 256 shorts (d_out interleaved).
__global__ __launch_bounds__(256) void fused_sage1_kernel(
    const uint4* __restrict__ featb4,            // xb, 16 uint4/row
    const int* __restrict__ rowptr,
    const int* __restrict__ deg_i,
    const int* __restrict__ csr_src,
    const unsigned short* __restrict__ wt,       // layer1 [128 cols][256 k]
    const float* __restrict__ bias,
    unsigned short* __restrict__ outb,           // h, pitch 256 shorts
    int N)
{
    __shared__ unsigned short Ms[64][136];
    __shared__ unsigned short As[64][72];
    __shared__ unsigned short Bs[128][72];

    const int t = threadIdx.x;
    const int lane = t & 63;
    const int wv = t >> 6;
    const int c = lane & 15;
    const int qb = lane & 48;
    const int Q = wv * 4 + (lane >> 4);          // quarter id 0..15
    const int block_row = blockIdx.x * 64;

    // ---- gather phase ----
    for (int j = 0; j < 4; ++j) {
        int row = Q * 4 + j;
        int n = block_row + row;
        if (n < N) {
            int start = rowptr[n];
            int dg = deg_i[n];
            float ga[8];
#pragma unroll
            for (int k = 0; k < 8; ++k) ga[k] = 0.f;

            for (int base = 0; base < dg; base += 16) {
                int rem = min(dg - base, 16);
                int idxw = (c < rem) ? csr_src[start + base + c] : 0;

                int e = 0;
                for (; e + 4 <= rem; e += 4) {
                    int i0 = __shfl(idxw, qb + e);
                    int i1 = __shfl(idxw, qb + e + 1);
                    int i2 = __shfl(idxw, qb + e + 2);
                    int i3 = __shfl(idxw, qb + e + 3);
                    uint4 u0 = featb4[(unsigned)((i0 << 4) | c)];
                    uint4 u1 = featb4[(unsigned)((i1 << 4) | c)];
                    uint4 u2 = featb4[(unsigned)((i2 << 4) | c)];
                    uint4 u3 = featb4[(unsigned)((i3 << 4) | c)];
                    upadd(u0.x, ga[0], ga[1]);
                    upadd(u0.y, ga[2], ga[3]);
                    upadd(u0.z, ga[4], ga[5]);
                    upadd(u0.w, ga[6], ga[7]);
                    upadd(u1.x, ga[0], ga[1]);
                    upadd(u1.y, ga[2], ga[3]);
                    upadd(u1.z, ga[4], ga[5]);
                    upadd(u1.w, ga[6], ga[7]);
                    upadd(u2.x, ga[0], ga[1]);
                    upadd(u2.y, ga[2], ga[3]);
                    upadd(u2.z, ga[4], ga[5]);
                    upadd(u2.w, ga[6], ga[7]);
                    upadd(u3.x, ga[0], ga[1]);
                    upadd(u3.y, ga[2], ga[3]);
                    upadd(u3.z, ga[4], ga[5]);
                    upadd(u3.w, ga[6], ga[7]);
                }
                for (; e < rem; ++e) {
                    int i0 = __shfl(idxw, qb + e);
                    uint4 u0 = featb4[(unsigned)((i0 << 4) | c)];
                    upadd(u0.x, ga[0], ga[1]);
                    upadd(u0.y, ga[2], ga[3]);
                    upadd(u0.z, ga[4], ga[5]);
                    upadd(u0.w, ga[6], ga[7]);
                }
            }

            float r = 1.0f / fmaxf((float)dg, 1.0f);
            uint4 o;
            o.x = ((unsigned)f2bf(ga[1] * r) << 16) | f2bf(ga[0] * r);
            o.y = ((unsigned)f2bf(ga[3] * r) << 16) | f2bf(ga[2] * r);
            o.z = ((unsigned)f2bf(ga[5] * r) << 16) | f2bf(ga[4] * r);
            o.w = ((unsigned)f2bf(ga[7] * r) << 16) | f2bf(ga[6] * r);
            *(uint4*)&Ms[row][c * 8] = o;
        } else {
            *(uint4*)&Ms[row][c * 8] = make_uint4(0, 0, 0, 0);
        }
    }
    __syncthreads();

    // ---- GEMM phase ----
    const unsigned short* xin = (const unsigned short*)featb4;
    const int w = wv;
    const int m = lane & 15;
    const int kq = lane >> 4;

    f32x4 acc[8];
#pragma unroll
    for (int i = 0; i < 8; ++i) acc[i] = (f32x4){0.f, 0.f, 0.f, 0.f};

    for (int chunk = 0; chunk < 4; ++chunk) {
        const bool is_mean = (chunk < 2);
        const int kbase = (chunk & 1) * 64;

        // ---- A tile from x (chunks 2-3 only; mean comes from Ms) ----
        if (!is_mean) {
            int row_l = t >> 2;
            int seg = t & 3;
            int grow = block_row + row_l;
            unsigned short* dstp = &As[row_l][seg * 16];
            if (grow < N) {
                const uint4* p = (const uint4*)(xin + (size_t)grow * F + kbase + seg * 16);
                ((uint4*)dstp)[0] = p[0];
                ((uint4*)dstp)[1] = p[1];
            } else {
                uint4 z = make_uint4(0, 0, 0, 0);
                ((uint4*)dstp)[0] = z;
                ((uint4*)dstp)[1] = z;
            }
        }
        // ---- B tile: 128 cols x 64 k from Wt ----
        {
            int cc = t >> 1;
            int half = t & 1;
            const uint4* p = (const uint4*)(wt + cc * 256 + chunk * 64 + half * 32);
            unsigned short* dstp = &Bs[cc][half * 32];
            ((uint4*)dstp)[0] = p[0];
            ((uint4*)dstp)[1] = p[1];
            ((uint4*)dstp)[2] = p[2];
            ((uint4*)dstp)[3] = p[3];
        }
        __syncthreads();

#pragma unroll
        for (int ks = 0; ks < 2; ++ks) {
            short8 a = is_mean
                ? *(const short8*)&Ms[w * 16 + m][chunk * 64 + ks * 32 + kq * 8]
                : *(const short8*)&As[w * 16 + m][ks * 32 + kq * 8];
#pragma unroll
            for (int tt = 0; tt < 8; ++tt) {
                short8 b = *(const short8*)&Bs[tt * 16 + m][ks * 32 + kq * 8];
                acc[tt] = __builtin_amdgcn_mfma_f32_16x16x32_bf16(a, b, acc[tt], 0, 0, 0);
            }
        }
        __syncthreads();
    }

    // ---- epilogue: relu + bf16 h, pitch 256 shorts ----
    float bb[8];
#pragma unroll
    for (int tt = 0; tt < 8; ++tt) bb[tt] = bias[tt * 16 + m];
    int rbase = block_row + w * 16 + kq * 4;
#pragma unroll
    for (int r = 0; r < 4; ++r) {
        int grow = rbase + r;
        if (grow < N) {
#pragma unroll
            for (int tt = 0; tt < 8; ++tt) {
                float v = fmaxf(acc[tt][r] + bb[tt], 0.f);
                outb[(size_t)grow * 256 + tt * 16 + m] = f2bf(v);
            }
        }
    }
}

// ---------------- MFMA GEMM (layer 2): out = mean2 @ Wl + h @ Wr + b ----------------
// MP/XP/OP: row pitches (in elems) of mean, x-input, output.
template <bool RELU, bool OUT_BF16, int MP, int XP, int OP>
__global__ __launch_bounds__(256) void sage_gemm_mfma(
    const unsigned short* __restrict__ meanb,
    const unsigned short* __restrict__ xin,
    const unsigned short* __restrict__ wt,   // [128 cols][256 k] bf16
    const float* __restrict__ bias,
    float* __restrict__ outp, unsigned short* __restrict__ outb, int N)
{
    __shared__ unsigned short As[64][72];    // stride 144 B: 16B-aligned, conflict-free b128
    __shared__ unsigned short Bs[128][72];

    const int t = threadIdx.x;
    const int block_row = blockIdx.x * 64;
    const int lane = t & 63;
    const int w = t >> 6;
    const int m = lane & 15;
    const int kq = lane >> 4;

    f32x4 acc[8];
#pragma unroll
    for (int i = 0; i < 8; ++i) acc[i] = (f32x4){0.f, 0.f, 0.f, 0.f};

    for (int chunk = 0; chunk < 4; ++chunk) {
        const bool is_mean = (chunk < 2);
        const int kbase = (chunk & 1) * 64;

        // ---- A tile: 64 rows x 64 k (each thread: 16 bf16 = 32 B) ----
        {
            int row_l = t >> 2;
            int seg = t & 3;
            int grow = block_row + row_l;
            unsigned short* dstp = &As[row_l][seg * 16];
            if (grow < N) {
                const unsigned short* srcp = is_mean
                    ? meanb + (size_t)grow * MP + kbase + seg * 16
                    : xin   + (size_t)grow * XP + kbase + seg * 16;
                const uint4* p = (const uint4*)srcp;
                ((uint4*)dstp)[0] = p[0];
                ((uint4*)dstp)[1] = p[1];
            } else {
                uint4 z = make_uint4(0, 0, 0, 0);
                ((uint4*)dstp)[0] = z;
                ((uint4*)dstp)[1] = z;
            }
        }
        // ---- B tile: 128 cols x 64 k from Wt (each thread: 32 bf16 = 64 B) ----
        {
            int c = t >> 1;
            int half = t & 1;
            const uint4* p = (const uint4*)(wt + c * 256 + chunk * 64 + half * 32);
            unsigned short* dstp = &Bs[c][half * 32];
            ((uint4*)dstp)[0] = p[0];
            ((uint4*)dstp)[1] = p[1];
            ((uint4*)dstp)[2] = p[2];
            ((uint4*)dstp)[3] = p[3];
        }
        __syncthreads();

        // ---- MFMA: A[m=lane&15][k=(lane>>4)*8+j], B[k][n=lane&15] ----
#pragma unroll
        for (int ks = 0; ks < 2; ++ks) {
            short8 a = *(const short8*)&As[w * 16 + m][ks * 32 + kq * 8];
#pragma unroll
            for (int tt = 0; tt < 8; ++tt) {
                short8 b = *(const short8*)&Bs[tt * 16 + m][ks * 32 + kq * 8];
                acc[tt] = __builtin_amdgcn_mfma_f32_16x16x32_bf16(a, b, acc[tt], 0, 0, 0);
            }
        }
        __syncthreads();
    }

    // ---- epilogue: C/D row=(lane>>4)*4+reg, col=lane&15 ----
    float bb[8];
#pragma unroll
    for (int tt = 0; tt < 8; ++tt) bb[tt] = bias[tt * 16 + m];
    int rbase = block_row + w * 16 + kq * 4;
#pragma unroll
    for (int r = 0; r < 4; ++r) {
        int grow = rbase + r;
        if (grow < N) {
#pragma unroll
            for (int tt = 0; tt < 8; ++tt) {
                float v = acc[tt][r] + bb[tt];
                if (RELU) v = fmaxf(v, 0.f);
                if (OUT_BF16)
                    outb[(size_t)grow * OP + tt * 16 + m] = f2bf(v);
                else
                    outp[(size_t)grow * OP + tt * 16 + m] = v;
            }
        }
    }
}

extern "C" void kernel_launch(void* const* d_in, const int* in_sizes, int n_in,
                              void* d_out, int out_size, void* d_ws, size_t ws_size,
                              hipStream_t stream) {
    const float* x    = (const float*)d_in[0];
    const int*   ei   = (const int*)d_in[1];    // int32 (harness converts int64)
    const float* W_l1 = (const float*)d_in[2];
    const float* W_r1 = (const float*)d_in[3];
    const float* b1   = (const float*)d_in[4];
    const float* W_l2 = (const float*)d_in[5];
    const float* W_r2 = (const float*)d_in[6];
    const float* b2   = (const float*)d_in[7];
    float* out        = (float*)d_out;

    const int N = N_NODES;
    const int E = N_EDGES;
    const int* srcv = ei;
    const int* dstv = ei + E;

    // ---- workspace layout (bytes); ws_size proven >= 33,337,344 ----
    const size_t rowptr_off = 400128;            // int[N]
    const size_t bb_off     = 800256;            // bucket_base int[NBK+1] (4096 reserved)
    const size_t csr_off    = 804352;            // int[1.6M] = 6.4 MB -> 7,204,352
    const size_t xb_off     = 7204352;           // bf16[N*F] = 25.6 MB -> 32,804,352
    const size_t wt_off     = 32804352;          // bf16[2][128][256] -> 32,935,424
    const size_t need_min   = 32935424;          // < proven 33,337,344
    // transients aliased into xb region (consumed by bucket_fill before cast):
    const size_t blkh_rel   = 0;                 // int[NSB*NBK]
    const size_t bbase_rel  = 1223168;           // int[NSB*NBK]
    const size_t stag_rel   = 2446336;           // uint[1.6M] -> 8,846,336 (< 25.6MB)

    if (ws_size < need_min) return;  // clean validation failure as diagnostic

    char* ws = (char*)d_ws;
    int* deg_i   = (int*)ws;
    int* rowptr  = (int*)(ws + rowptr_off);
    int* bucket_base = (int*)(ws + bb_off);
    int* csr_src = (int*)(ws + csr_off);
    unsigned short* xb = (unsigned short*)(ws + xb_off);
    int* blkhist = (int*)(ws + xb_off + blkh_rel);
    int* bbase   = (int*)(ws + xb_off + bbase_rel);
    unsigned* staging = (unsigned*)(ws + xb_off + stag_rel);
    unsigned short* wt = (unsigned short*)(ws + wt_off);
    // h lives interleaved in d_out: row n -> bytes [n*512, n*512+256)
    unsigned short* hb = (unsigned short*)d_out;

    // ---- contention-free bucket permute -> csr_src (+deg/rowptr fused) ----
    blkhist_kernel<<<dim3(NSB), dim3(256), 0, stream>>>(dstv, blkhist, E);
    bucket_scan_kernel<<<dim3(NBK), dim3(512), 0, stream>>>(blkhist, bbase, bucket_base);
    bucket_base_scan_kernel<<<dim3(1), dim3(1024), 0, stream>>>(bucket_base);
    bucket_scatter_kernel<<<dim3(NSB), dim3(256), 0, stream>>>(
        srcv, dstv, bbase, bucket_base, staging, E);
    bucket_fill_kernel<<<dim3(NBK), dim3(256), 0, stream>>>(
        staging, bucket_base, rowptr, deg_i, csr_src, N);

    // ---- weight prep + x cast (after staging consumed) ----
    wt_kernel<<<dim3(256), dim3(256), 0, stream>>>(W_l1, W_r1, W_l2, W_r2, wt);
    cast_kernel<<<dim3((N * F / 4 + 255) / 256), dim3(256), 0, stream>>>(x, xb, N * F / 4);

    dim3 ablock(256), agrid((N + 15) / 16);
    dim3 gblock(256), ggrid((N + 63) / 64);

    // ---- layer 1 FUSED: gather(xb) + GEMM -> h bf16 interleaved in d_out ----
    fused_sage1_kernel<<<ggrid, gblock, 0, stream>>>(
        (const uint4*)xb, rowptr, deg_i, csr_src, wt, b1, hb, N);

    // ---- layer 2: mean2(h) -> xb contiguous; gemm2 -> fp32 d_out ----
    csr_mean_kernel<5, 4><<<agrid, ablock, 0, stream>>>(
        (const uint4*)d_out, rowptr, deg_i, csr_src, (uint4*)xb, N);
    sage_gemm_mfma<false, false, 128, 256, 128><<<ggrid, gblock, 0, stream>>>(
        xb, hb, wt + 32768, b2, out, nullptr, N);
}

// Round 5
// 322.780 us; speedup vs baseline: 1.0588x; 1.0588x over previous
//
#include <hip/hip_runtime.h>
#include <hip/hip_bf16.h>

// 2-layer GraphSAGE mean-aggr, N=100000, E=1600000, F=128.
// R15: revert R14 fusion (occupancy collapse 24.8%, 2.37TB/s: gather is
// service-rate bound and needs resident waves; 44KB-LDS fused kernel halved
// them). Back to split R12/R13 structure (means = 58us each, the measured
// random-gather wall), plus three non-mean fixes:
//  1) blkhist transposed to [bucket][block]: bucket_scan reads coalesced;
//     scan rewritten wave-per-bucket (shfl_up, no barriers).
//  2) transients (blkhist/bbase/staging) moved from xb region into d_out
//     (free until mean1) -> cast no longer depends on bucket chain.
//  3) wt merged into blkhist dispatch; cast merged into scatter dispatch
//     (grid split by blockIdx). 11 kernels -> 9, independent streaming
//     overlapped with bucket chain.
// Gather/pack/MFMA/epilogue identical to R12/R13 -> bit-identical output.

#define N_NODES 100000
#define N_EDGES 1600000
#define F 128
#define NBK 782       // ceil(N/128) buckets (128 nodes each)
#define NSB 391       // scatter blocks (4096 edges each)

typedef __attribute__((ext_vector_type(8))) short short8;
typedef __attribute__((ext_vector_type(4))) float f32x4;

__device__ __forceinline__ unsigned short f2bf(float f) {
    union { __hip_bfloat16 h; unsigned short u; } cv;
    cv.h = __float2bfloat16(f);
    return cv.u;
}
// unpack packed bf16 pair and accumulate
__device__ __forceinline__ void upadd(unsigned u, float& a, float& b) {
    a += __uint_as_float(u << 16);
    b += __uint_as_float(u & 0xffff0000u);
}

// ---------------- blkhist (transposed out) + wt, one dispatch ----------------
// blocks [0,NSB): per-4096-edge-block bucket histogram -> blkhist[bucket][blk]
// blocks [NSB,NSB+256): weight transpose+cast Wt[layer][col][k] bf16
__global__ __launch_bounds__(256) void blkhist_wt_kernel(
    const int* __restrict__ dst, int* __restrict__ blkhist,
    const float* __restrict__ Wl1, const float* __restrict__ Wr1,
    const float* __restrict__ Wl2, const float* __restrict__ Wr2,
    unsigned short* __restrict__ wt, int E)
{
    __shared__ int h[NBK];
    int t = threadIdx.x, blk = blockIdx.x;
    if (blk < NSB) {
        for (int i = t; i < NBK; i += 256) h[i] = 0;
        __syncthreads();
        int base = blk * 4096;
        int end = min(base + 4096, E);
        for (int e = base + t; e < end; e += 256) atomicAdd(&h[dst[e] >> 7], 1);
        __syncthreads();
        for (int i = t; i < NBK; i += 256) blkhist[i * NSB + blk] = h[i];
    } else {
        int e = (blk - NSB) * 256 + t;   // 0..65535
        int layer = e >> 15;
        int idx = e & 32767;
        int k = idx >> 7;      // 0..255
        int c = idx & 127;
        const float* W = (layer == 0) ? (k < 128 ? Wl1 : Wr1)
                                      : (k < 128 ? Wl2 : Wr2);
        float v = W[(k & 127) * 128 + c];
        wt[layer * 32768 + c * 256 + k] = f2bf(v);
    }
}

// ---------------- bucket_scan: one WAVE per bucket, shfl scan ----------------
// Reads blkhist[bucket][t] coalesced; writes bucket-relative block bases
// bbase[t][bucket] (scatter reads that row-contiguous); btotal[b] = total.
__global__ __launch_bounds__(256) void bucket_scan_kernel(
    const int* __restrict__ blkhist,   // [NBK][NSB]
    int* __restrict__ bbase,           // [NSB][NBK]
    int* __restrict__ btotal)
{
    int wv = threadIdx.x >> 6, lane = threadIdx.x & 63;
    int b = blockIdx.x * 4 + wv;
    if (b >= NBK) return;
    const int* row = blkhist + (size_t)b * NSB;
    int carry = 0;
    for (int base = 0; base < NSB; base += 64) {
        int t = base + lane;
        int v = (t < NSB) ? row[t] : 0;
        int s = v;
#pragma unroll
        for (int off = 1; off < 64; off <<= 1) {
            int u = __shfl_up(s, off);
            if (lane >= off) s += u;
        }
        if (t < NSB) bbase[t * NBK + b] = carry + s - v;   // exclusive, bucket-relative
        carry += __shfl(s, 63);
    }
    if (lane == 0) btotal[b] = carry;
}

// single block: exclusive scan of bucket totals in-place; bb[NBK] = E sentinel
__global__ __launch_bounds__(1024) void bucket_base_scan_kernel(int* bb)
{
    __shared__ int s[1024];
    int t = threadIdx.x;
    int v = (t < NBK) ? bb[t] : 0;
    s[t] = v;
    __syncthreads();
#pragma unroll
    for (int off = 1; off < 1024; off <<= 1) {
        int u = (t >= off) ? s[t - off] : 0;
        __syncthreads();
        s[t] += u;
        __syncthreads();
    }
    if (t <= NBK) bb[t] = (t == 0) ? 0 : s[t - 1];
}

// ---------------- scatter (+cast riding along), one dispatch ----------------
// blocks [0,NSB): bucket scatter -> staging (in d_out region)
// blocks [NSB,NSB+12500): cast x fp32 -> xb bf16 (independent of chain)
__global__ __launch_bounds__(256) void scatter_cast_kernel(
    const int* __restrict__ src, const int* __restrict__ dst,
    const int* __restrict__ bbase, const int* __restrict__ bucket_base,
    unsigned* __restrict__ staging,
    const float* __restrict__ x, unsigned short* __restrict__ xb,
    int E, int total4)
{
    __shared__ int cur[NBK];
    int t = threadIdx.x, blk = blockIdx.x;
    if (blk < NSB) {
        for (int i = t; i < NBK; i += 256)
            cur[i] = bbase[blk * NBK + i] + bucket_base[i];
        __syncthreads();
        int base = blk * 4096;
        int end = min(base + 4096, E);
        for (int e = base + t; e < end; e += 256) {
            int d = dst[e];
            int p = atomicAdd(&cur[d >> 7], 1);
            staging[p] = ((unsigned)src[e] << 7) | (unsigned)(d & 127);
        }
    } else {
        int i = (blk - NSB) * 256 + t;
        if (i < total4) {
            float4 v = ((const float4*)x)[i];
            unsigned lo = ((unsigned)f2bf(v.y) << 16) | f2bf(v.x);
            unsigned hi = ((unsigned)f2bf(v.w) << 16) | f2bf(v.z);
            ((uint2*)xb)[i] = make_uint2(lo, hi);
        }
    }
}

// pass 1: LDS-histogram the bucket's 128 node slots -> deg/rowptr; pass 2: fill
__global__ __launch_bounds__(256) void bucket_fill_kernel(
    const unsigned* __restrict__ staging, const int* __restrict__ bucket_base,
    int* __restrict__ rowptr, int* __restrict__ deg_i,
    int* __restrict__ csr_src, int N)
{
    __shared__ int cnt[128];
    __shared__ int sc[128];
    __shared__ int cur[128];
    int b = blockIdx.x;
    int t = threadIdx.x;
    if (t < 128) cnt[t] = 0;
    __syncthreads();
    int start = bucket_base[b];
    int end = bucket_base[b + 1];
    for (int e = start + t; e < end; e += 256)
        atomicAdd(&cnt[staging[e] & 127], 1);
    __syncthreads();
    // exclusive scan over 128 slot counts
    if (t < 128) sc[t] = cnt[t];
    __syncthreads();
#pragma unroll
    for (int off = 1; off < 128; off <<= 1) {
        int v = (t < 128 && t >= off) ? sc[t - off] : 0;
        __syncthreads();
        if (t < 128) sc[t] += v;
        __syncthreads();
    }
    if (t < 128) {
        int excl = sc[t] - cnt[t];
        cur[t] = start + excl;
        int node = (b << 7) + t;
        if (node < N) {
            rowptr[node] = start + excl;
            deg_i[node] = cnt[t];
        }
    }
    __syncthreads();
    for (int e = start + t; e < end; e += 256) {
        unsigned u = staging[e];
        int p = atomicAdd(&cur[u & 127], 1);
        csr_src[p] = (int)(u >> 7);
    }
}

// ---------------- aggregate: mean over in-neighbors (bf16 src) ----------------
// R13 structure: one node per QUARTER-wave; lane c owns 16B (cols 8c..8c+7).
// SS = log2(src row pitch in uint4); DS = log2(dst row pitch in uint4).
template <int SS, int DS>
__global__ __launch_bounds__(256) void csr_mean_kernel(
    const uint4* __restrict__ featb4, const int* __restrict__ rowptr,
    const int* __restrict__ deg_i, const int* __restrict__ csr_src,
    uint4* __restrict__ mean4, int N)
{
    int lane = threadIdx.x & 63;
    int wv = threadIdx.x >> 6;                     // wave in block 0..3
    int c = lane & 15;                             // 16B column segment
    int qb = lane & 48;                            // quarter's shfl base
    int n = blockIdx.x * 16 + wv * 4 + (lane >> 4);
    if (n >= N) return;
    int start = rowptr[n];
    int dg = deg_i[n];

    float acc[8];
#pragma unroll
    for (int j = 0; j < 8; ++j) acc[j] = 0.f;

    for (int base = 0; base < dg; base += 16) {
        int rem = min(dg - base, 16);
        int idxw = (c < rem) ? csr_src[start + base + c] : 0;

        int e = 0;
        for (; e + 4 <= rem; e += 4) {
            int i0 = __shfl(idxw, qb + e);
            int i1 = __shfl(idxw, qb + e + 1);
            int i2 = __shfl(idxw, qb + e + 2);
            int i3 = __shfl(idxw, qb + e + 3);
            uint4 u0 = featb4[(unsigned)((i0 << SS) | c)];
            uint4 u1 = featb4[(unsigned)((i1 << SS) | c)];
            uint4 u2 = featb4[(unsigned)((i2 << SS) | c)];
            uint4 u3 = featb4[(unsigned)((i3 << SS) | c)];
            upadd(u0.x, acc[0], acc[1]);
            upadd(u0.y, acc[2], acc[3]);
            upadd(u0.z, acc[4], acc[5]);
            upadd(u0.w, acc[6], acc[7]);
            upadd(u1.x, acc[0], acc[1]);
            upadd(u1.y, acc[2], acc[3]);
            upadd(u1.z, acc[4], acc[5]);
            upadd(u1.w, acc[6], acc[7]);
            upadd(u2.x, acc[0], acc[1]);
            upadd(u2.y, acc[2], acc[3]);
            upadd(u2.z, acc[4], acc[5]);
            upadd(u2.w, acc[6], acc[7]);
            upadd(u3.x, acc[0], acc[1]);
            upadd(u3.y, acc[2], acc[3]);
            upadd(u3.z, acc[4], acc[5]);
            upadd(u3.w, acc[6], acc[7]);
        }
        for (; e < rem; ++e) {
            int i0 = __shfl(idxw, qb + e);
            uint4 u0 = featb4[(unsigned)((i0 << SS) | c)];
            upadd(u0.x, acc[0], acc[1]);
            upadd(u0.y, acc[2], acc[3]);
            upadd(u0.z, acc[4], acc[5]);
            upadd(u0.w, acc[6], acc[7]);
        }
    }

    float r = 1.0f / fmaxf((float)dg, 1.0f);
    uint4 o;
    o.x = ((unsigned)f2bf(acc[1] * r) << 16) | f2bf(acc[0] * r);
    o.y = ((unsigned)f2bf(acc[3] * r) << 16) | f2bf(acc[2] * r);
    o.z = ((unsigned)f2bf(acc[5] * r) << 16) | f2bf(acc[4] * r);
    o.w = ((unsigned)f2bf(acc[7] * r) << 16) | f2bf(acc[6] * r);
    mean4[(unsigned)((n << DS) | c)] = o;
}

// ---------------- MFMA GEMM: out = mean @ Wl + x @ Wr + b (+relu) ----------------
// MP/XP/OP: row pitches (in elems) of mean, x-input, output.
// Aliasing-safe: block reads ONLY its own rows; epilogue writes those same
// rows after all reads (ordered by __syncthreads within block).
template <bool RELU, bool OUT_BF16, int MP, int XP, int OP>
__global__ __launch_bounds__(256) void sage_gemm_mfma(
    const unsigned short* __restrict__ meanb,
    const unsigned short* __restrict__ xin,
    const unsigned short* __restrict__ wt,   // [128 cols][256 k] bf16
    const float* __restrict__ bias,
    float* __restrict__ outp, unsigned short* __restrict__ outb, int N)
{
    __shared__ unsigned short As[64][72];    // stride 144 B: 16B-aligned, conflict-free b128
    __shared__ unsigned short Bs[128][72];

    const int t = threadIdx.x;
    const int block_row = blockIdx.x * 64;
    const int lane = t & 63;
    const int w = t >> 6;
    const int m = lane & 15;
    const int kq = lane >> 4;

    f32x4 acc[8];
#pragma unroll
    for (int i = 0; i < 8; ++i) acc[i] = (f32x4){0.f, 0.f, 0.f, 0.f};

    for (int chunk = 0; chunk < 4; ++chunk) {
        const bool is_mean = (chunk < 2);
        const int kbase = (chunk & 1) * 64;

        // ---- A tile: 64 rows x 64 k (each thread: 16 bf16 = 32 B) ----
        {
            int row_l = t >> 2;
            int seg = t & 3;
            int grow = block_row + row_l;
            unsigned short* dstp = &As[row_l][seg * 16];
            if (grow < N) {
                const unsigned short* srcp = is_mean
                    ? meanb + (size_t)grow * MP + kbase + seg * 16
                    : xin   + (size_t)grow * XP + kbase + seg * 16;
                const uint4* p = (const uint4*)srcp;
                ((uint4*)dstp)[0] = p[0];
                ((uint4*)dstp)[1] = p[1];
            } else {
                uint4 z = make_uint4(0, 0, 0, 0);
                ((uint4*)dstp)[0] = z;
                ((uint4*)dstp)[1] = z;
            }
        }
        // ---- B tile: 128 cols x 64 k from Wt (each thread: 32 bf16 = 64 B) ----
        {
            int c = t >> 1;
            int half = t & 1;
            const uint4* p = (const uint4*)(wt + c * 256 + chunk * 64 + half * 32);
            unsigned short* dstp = &Bs[c][half * 32];
            ((uint4*)dstp)[0] = p[0];
            ((uint4*)dstp)[1] = p[1];
            ((uint4*)dstp)[2] = p[2];
            ((uint4*)dstp)[3] = p[3];
        }
        __syncthreads();

        // ---- MFMA: A[m=lane&15][k=(lane>>4)*8+j], B[k][n=lane&15] ----
#pragma unroll
        for (int ks = 0; ks < 2; ++ks) {
            short8 a = *(const short8*)&As[w * 16 + m][ks * 32 + kq * 8];
#pragma unroll
            for (int tt = 0; tt < 8; ++tt) {
                short8 b = *(const short8*)&Bs[tt * 16 + m][ks * 32 + kq * 8];
                acc[tt] = __builtin_amdgcn_mfma_f32_16x16x32_bf16(a, b, acc[tt], 0, 0, 0);
            }
        }
        __syncthreads();
    }

    // ---- epilogue: C/D row=(lane>>4)*4+reg, col=lane&15 ----
    float bb[8];
#pragma unroll
    for (int tt = 0; tt < 8; ++tt) bb[tt] = bias[tt * 16 + m];
    int rbase = block_row + w * 16 + kq * 4;
#pragma unroll
    for (int r = 0; r < 4; ++r) {
        int grow = rbase + r;
        if (grow < N) {
#pragma unroll
            for (int tt = 0; tt < 8; ++tt) {
                float v = acc[tt][r] + bb[tt];
                if (RELU) v = fmaxf(v, 0.f);
                if (OUT_BF16)
                    outb[(size_t)grow * OP + tt * 16 + m] = f2bf(v);
                else
                    outp[(size_t)grow * OP + tt * 16 + m] = v;
            }
        }
    }
}

extern "C" void kernel_launch(void* const* d_in, const int* in_sizes, int n_in,
                              void* d_out, int out_size, void* d_ws, size_t ws_size,
                              hipStream_t stream) {
    const float* x    = (const float*)d_in[0];
    const int*   ei   = (const int*)d_in[1];    // int32 (harness converts int64)
    const float* W_l1 = (const float*)d_in[2];
    const float* W_r1 = (const float*)d_in[3];
    const float* b1   = (const float*)d_in[4];
    const float* W_l2 = (const float*)d_in[5];
    const float* W_r2 = (const float*)d_in[6];
    const float* b2   = (const float*)d_in[7];
    float* out        = (float*)d_out;

    const int N = N_NODES;
    const int E = N_EDGES;
    const int* srcv = ei;
    const int* dstv = ei + E;

    // ---- workspace layout (bytes); ws_size proven >= 33,337,344 ----
    const size_t rowptr_off = 400128;            // int[N]
    const size_t bb_off     = 800256;            // bucket_base int[NBK+1] (4096 reserved)
    const size_t csr_off    = 804352;            // int[1.6M] = 6.4 MB -> 7,204,352
    const size_t xb_off     = 7204352;           // bf16[N*F] = 25.6 MB -> 32,804,352
    const size_t wt_off     = 32804352;          // bf16[2][128][256] -> 32,935,424
    const size_t need_min   = 32935424;          // < proven 33,337,344
    // transients now aliased into d_out (free until mean1 overwrites):
    const size_t blkh_rel   = 0;                 // int[NBK*NSB] = 1,223,048
    const size_t bbase_rel  = 1223168;           // int[NSB*NBK] = 1,223,048
    const size_t stag_rel   = 2446336;           // uint[1.6M] -> 8,846,336 (< 51.2MB)

    if (ws_size < need_min) return;  // clean validation failure as diagnostic

    char* ws = (char*)d_ws;
    int* deg_i   = (int*)ws;
    int* rowptr  = (int*)(ws + rowptr_off);
    int* bucket_base = (int*)(ws + bb_off);
    int* csr_src = (int*)(ws + csr_off);
    unsigned short* xb = (unsigned short*)(ws + xb_off);
    unsigned short* wt = (unsigned short*)(ws + wt_off);
    char* dob = (char*)d_out;
    int* blkhist = (int*)(dob + blkh_rel);
    int* bbase   = (int*)(dob + bbase_rel);
    unsigned* staging = (unsigned*)(dob + stag_rel);
    // means live interleaved in d_out: row n -> bytes [n*512, n*512+256)
    uint4* mean4 = (uint4*)d_out;
    const unsigned short* meanb = (const unsigned short*)d_out;

    const int total4 = N * F / 4;                // 3,200,000 float4s
    const int cast_blocks = total4 / 256;        // 12500

    // ---- bucket permute chain (transients in d_out), wt+cast riding along ----
    blkhist_wt_kernel<<<dim3(NSB + 256), dim3(256), 0, stream>>>(
        dstv, blkhist, W_l1, W_r1, W_l2, W_r2, wt, E);
    bucket_scan_kernel<<<dim3((NBK + 3) / 4), dim3(256), 0, stream>>>(
        blkhist, bbase, bucket_base);
    bucket_base_scan_kernel<<<dim3(1), dim3(1024), 0, stream>>>(bucket_base);
    scatter_cast_kernel<<<dim3(NSB + cast_blocks), dim3(256), 0, stream>>>(
        srcv, dstv, bbase, bucket_base, staging, x, xb, E, total4);
    bucket_fill_kernel<<<dim3(NBK), dim3(256), 0, stream>>>(
        staging, bucket_base, rowptr, deg_i, csr_src, N);

    dim3 ablock(256), agrid((N + 15) / 16);
    dim3 gblock(256), ggrid((N + 63) / 64);

    // ---- layer 1: mean1(xb) -> d_out interleaved; gemm1 -> h bf16 into xb ----
    csr_mean_kernel<4, 5><<<agrid, ablock, 0, stream>>>(
        (const uint4*)xb, rowptr, deg_i, csr_src, mean4, N);
    sage_gemm_mfma<true, true, 256, 128, 128><<<ggrid, gblock, 0, stream>>>(
        meanb, xb, wt, b1, nullptr, xb, N);

    // ---- layer 2: mean2(xb=h) -> d_out interleaved; gemm2 -> fp32 d_out ----
    csr_mean_kernel<4, 5><<<agrid, ablock, 0, stream>>>(
        (const uint4*)xb, rowptr, deg_i, csr_src, mean4, N);
    sage_gemm_mfma<false, false, 256, 128, 128><<<ggrid, gblock, 0, stream>>>(
        meanb, xb, wt + 32768, b2, out, nullptr, N);
}